// Round 1
// baseline (780.001 us; speedup 1.0000x reference)
//
#include <hip/hip_runtime.h>
#include <math.h>

#define NN 50000
#define NE 800000
#define DF 128

// ---------------- degree histogram ----------------
__global__ __launch_bounds__(256) void hist_kernel(const int* __restrict__ dstv, int* __restrict__ cnt, int e) {
    int t = blockIdx.x * 256 + threadIdx.x;
    if (t < e) atomicAdd(&cnt[dstv[t]], 1);
}

__global__ __launch_bounds__(256) void dinv_kernel(const int* __restrict__ cnt, float* __restrict__ dinv, int n) {
    int t = blockIdx.x * 256 + threadIdx.x;
    if (t < n) dinv[t] = rsqrtf((float)cnt[t] + 1.0f);  // +1 self loop
}

// ---------------- exclusive scan (single block, 1024 threads) ----------------
__global__ __launch_bounds__(1024) void scan_kernel(const int* __restrict__ cnt, int* __restrict__ rp,
                                                    int* __restrict__ fill, int n) {
    __shared__ int wsum[16];
    __shared__ int s_run;
    const int lane = threadIdx.x & 63;
    const int wid = threadIdx.x >> 6;
    if (threadIdx.x == 0) s_run = 0;
    __syncthreads();
    for (int base = 0; base < n; base += 1024) {
        int i = base + (int)threadIdx.x;
        int v = (i < n) ? cnt[i] : 0;
        int xval = v;
        #pragma unroll
        for (int offd = 1; offd < 64; offd <<= 1) {
            int y = __shfl_up(xval, offd);
            if (lane >= offd) xval += y;
        }
        if (lane == 63) wsum[wid] = xval;
        __syncthreads();
        if (threadIdx.x < 16) {
            int w = wsum[threadIdx.x];
            #pragma unroll
            for (int offd = 1; offd < 16; offd <<= 1) {
                int y = __shfl_up(w, offd);
                if ((int)threadIdx.x >= offd) w += y;
            }
            wsum[threadIdx.x] = w;  // inclusive scan of wave sums
        }
        __syncthreads();
        int wave_excl = (wid == 0) ? 0 : wsum[wid - 1];
        int run = s_run;
        int excl = run + wave_excl + (xval - v);
        if (i < n) { rp[i] = excl; fill[i] = excl; }
        __syncthreads();
        if (threadIdx.x == 1023) s_run = run + wsum[15];
        __syncthreads();
    }
    if (threadIdx.x == 0) rp[n] = s_run;
}

// ---------------- CSR fill ----------------
__global__ __launch_bounds__(256) void fill_kernel(const int* __restrict__ srcv, const int* __restrict__ dstv,
                                                   int* __restrict__ fill, int* __restrict__ colv, int e) {
    int t = blockIdx.x * 256 + threadIdx.x;
    if (t < e) {
        int d = dstv[t];
        int pos = atomicAdd(&fill[d], 1);
        colv[pos] = srcv[t];
    }
}

// ---------------- H = X @ W  (fp32, W staged in LDS, 8 rows per wave) ----------------
__global__ __launch_bounds__(256) void gemm128_kernel(const float* __restrict__ X, const float* __restrict__ W,
                                                      float* __restrict__ H, int n) {
    __shared__ float Ws[DF * DF];  // 64 KiB, exactly the static limit -> 2 blocks/CU
    {
        const float4* Wsrc = (const float4*)W;
        float4* Wd = (float4*)Ws;
        #pragma unroll
        for (int t = 0; t < 16; t++) Wd[threadIdx.x + 256 * t] = Wsrc[threadIdx.x + 256 * t];
    }
    __syncthreads();  // NOTE: all threads reach this before any row-guard exit
    const int lane = threadIdx.x & 63;
    const int wv = __builtin_amdgcn_readfirstlane((int)(threadIdx.x >> 6));
    const int row0 = (blockIdx.x * 4 + wv) * 8;  // wave-uniform -> x loads scalarize
    if (row0 < n) {
        const float* __restrict__ xrow = X + (size_t)row0 * DF;
        float acc0[8], acc1[8];
        #pragma unroll
        for (int r = 0; r < 8; r++) { acc0[r] = 0.f; acc1[r] = 0.f; }
        #pragma unroll 4
        for (int k = 0; k < DF; k++) {
            // lane covers cols {lane, lane+64}: bank = lane%32, 2-way conflict = free
            float w0 = Ws[k * DF + lane];
            float w1 = Ws[k * DF + 64 + lane];
            #pragma unroll
            for (int r = 0; r < 8; r++) {
                float xv = xrow[r * DF + k];  // wave-uniform scalar load
                acc0[r] = fmaf(xv, w0, acc0[r]);
                acc1[r] = fmaf(xv, w1, acc1[r]);
            }
        }
        #pragma unroll
        for (int r = 0; r < 8; r++) {
            if (row0 + r < n) {
                H[(size_t)(row0 + r) * DF + lane] = acc0[r];
                H[(size_t)(row0 + r) * DF + 64 + lane] = acc1[r];
            }
        }
    }
}

// ---------------- aggregation: one wave per dst node, fused bias+activation ----------------
// out[i] = act( dinv[i] * sum_{src in row i} dinv[src]*H[src] + dinv[i]^2 * H[i] + b )
__global__ __launch_bounds__(256) void agg_kernel(const float* __restrict__ H, const int* __restrict__ rp,
                                                  const int* __restrict__ colv, const float* __restrict__ dinv,
                                                  const float* __restrict__ bias, float* __restrict__ out,
                                                  int n, int act) {
    const int lane = threadIdx.x & 63;
    const int i = blockIdx.x * 4 + (threadIdx.x >> 6);
    if (i >= n) return;
    const int start = rp[i];
    const int end = rp[i + 1];
    float accx = 0.f, accy = 0.f;
    for (int base = start; base < end; base += 64) {
        int cnt = end - base;
        if (cnt > 64) cnt = 64;
        int msrc = 0;
        float mdv = 0.f;
        if (lane < cnt) {                 // coalesced batch-load of edge srcs + their dinv
            msrc = colv[base + lane];
            mdv = dinv[msrc];
        }
        int j = 0;
        for (; j + 4 <= cnt; j += 4) {    // 4 gathers in flight per iteration
            int s0 = __shfl(msrc, j), s1 = __shfl(msrc, j + 1);
            int s2 = __shfl(msrc, j + 2), s3 = __shfl(msrc, j + 3);
            float d0 = __shfl(mdv, j), d1 = __shfl(mdv, j + 1);
            float d2 = __shfl(mdv, j + 2), d3 = __shfl(mdv, j + 3);
            float2 h0 = *(const float2*)(H + (size_t)s0 * DF + 2 * lane);
            float2 h1 = *(const float2*)(H + (size_t)s1 * DF + 2 * lane);
            float2 h2 = *(const float2*)(H + (size_t)s2 * DF + 2 * lane);
            float2 h3 = *(const float2*)(H + (size_t)s3 * DF + 2 * lane);
            accx = fmaf(d0, h0.x, accx); accy = fmaf(d0, h0.y, accy);
            accx = fmaf(d1, h1.x, accx); accy = fmaf(d1, h1.y, accy);
            accx = fmaf(d2, h2.x, accx); accy = fmaf(d2, h2.y, accy);
            accx = fmaf(d3, h3.x, accx); accy = fmaf(d3, h3.y, accy);
        }
        for (; j < cnt; j++) {
            int s = __shfl(msrc, j);
            float d = __shfl(mdv, j);
            float2 h = *(const float2*)(H + (size_t)s * DF + 2 * lane);
            accx = fmaf(d, h.x, accx); accy = fmaf(d, h.y, accy);
        }
    }
    float di = dinv[i];
    float2 hv = *(const float2*)(H + (size_t)i * DF + 2 * lane);
    float2 bv = *(const float2*)(bias + 2 * lane);
    float ox = fmaf(di, accx, di * di * hv.x) + bv.x;
    float oy = fmaf(di, accy, di * di * hv.y) + bv.y;
    if (act == 0) {  // ELU(alpha=1)
        ox = ox > 0.f ? ox : expm1f(ox);
        oy = oy > 0.f ? oy : expm1f(oy);
    } else {  // ReLU
        ox = fmaxf(ox, 0.f);
        oy = fmaxf(oy, 0.f);
    }
    float2 ov; ov.x = ox; ov.y = oy;
    *(float2*)(out + (size_t)i * DF + 2 * lane) = ov;
}

extern "C" void kernel_launch(void* const* d_in, const int* in_sizes, int n_in,
                              void* d_out, int out_size, void* d_ws, size_t ws_size,
                              hipStream_t stream) {
    const float* x  = (const float*)d_in[0];
    const float* W1 = (const float*)d_in[1];
    const float* b1 = (const float*)d_in[2];
    const float* W2 = (const float*)d_in[3];
    const float* b2 = (const float*)d_in[4];
    const float* W3 = (const float*)d_in[5];
    const float* b3 = (const float*)d_in[6];
    const float* W4 = (const float*)d_in[7];
    const float* b4 = (const float*)d_in[8];
    const int* ei1 = (const int*)d_in[9];
    const int* ei2 = (const int*)d_in[10];
    const int *src1 = ei1, *dst1 = ei1 + NE;
    const int *src2 = ei2, *dst2 = ei2 + NE;

    // ---- workspace carve-out (512B aligned). Total ~59.3 MB. ----
    char* ws = (char*)d_ws;
    size_t off = 0;
    auto carve = [&](size_t bytes) -> void* {
        void* p = (void*)(ws + off);
        off += (bytes + 511) & ~(size_t)511;
        return p;
    };
    int* cnt1 = (int*)carve((size_t)NN * 4);
    int* cnt2 = (int*)carve((size_t)NN * 4);
    size_t cnt_bytes = off;  // contiguous region to zero
    float* dinv1 = (float*)carve((size_t)NN * 4);
    float* dinv2 = (float*)carve((size_t)NN * 4);
    int* rp1 = (int*)carve((size_t)(NN + 1) * 4);
    int* rp2 = (int*)carve((size_t)(NN + 1) * 4);
    int* fill1 = (int*)carve((size_t)NN * 4);
    int* fill2 = (int*)carve((size_t)NN * 4);
    int* col1 = (int*)carve((size_t)NE * 4);
    int* col2 = (int*)carve((size_t)NE * 4);
    float* hpre = (float*)carve((size_t)NN * DF * 4);
    float* hbuf = (float*)carve((size_t)NN * DF * 4);

    float* outz  = (float*)d_out;               // z  = layer-2 output
    float* outxr = (float*)d_out + (size_t)NN * DF;  // xr = layer-4 output

    const int gE = (NE + 255) / 256;
    const int gN = (NN + 255) / 256;
    const int gGemm = ((NN + 7) / 8 + 3) / 4;   // 8 rows/wave, 4 waves/block
    const int gAgg = (NN + 3) / 4;              // 1 node/wave

    // ---- graph preprocessing (per launch; no persistent state) ----
    hipMemsetAsync(cnt1, 0, cnt_bytes, stream);
    hist_kernel<<<gE, 256, 0, stream>>>(dst1, cnt1, NE);
    hist_kernel<<<gE, 256, 0, stream>>>(dst2, cnt2, NE);
    dinv_kernel<<<gN, 256, 0, stream>>>(cnt1, dinv1, NN);
    dinv_kernel<<<gN, 256, 0, stream>>>(cnt2, dinv2, NN);
    scan_kernel<<<1, 1024, 0, stream>>>(cnt1, rp1, fill1, NN);
    scan_kernel<<<1, 1024, 0, stream>>>(cnt2, rp2, fill2, NN);
    fill_kernel<<<gE, 256, 0, stream>>>(src1, dst1, fill1, col1, NE);
    fill_kernel<<<gE, 256, 0, stream>>>(src2, dst2, fill2, col2, NE);

    // ---- layer 1: ELU(gcn(x, ei1, W1, b1)) -> hbuf ----
    gemm128_kernel<<<gGemm, 256, 0, stream>>>(x, W1, hpre, NN);
    agg_kernel<<<gAgg, 256, 0, stream>>>(hpre, rp1, col1, dinv1, b1, hbuf, NN, 0);
    // ---- layer 2: z = ELU(gcn(hbuf, ei2, W2, b2)) -> d_out[0:] ----
    gemm128_kernel<<<gGemm, 256, 0, stream>>>(hbuf, W2, hpre, NN);
    agg_kernel<<<gAgg, 256, 0, stream>>>(hpre, rp2, col2, dinv2, b2, outz, NN, 0);
    // ---- layer 3: ELU(gcn(z, ei1, W3, b3)) -> hbuf ----
    gemm128_kernel<<<gGemm, 256, 0, stream>>>(outz, W3, hpre, NN);
    agg_kernel<<<gAgg, 256, 0, stream>>>(hpre, rp1, col1, dinv1, b3, hbuf, NN, 0);
    // ---- layer 4: xr = ReLU(gcn(hbuf, ei2, W4, b4)) -> d_out[N*DF:] ----
    gemm128_kernel<<<gGemm, 256, 0, stream>>>(hbuf, W4, hpre, NN);
    agg_kernel<<<gAgg, 256, 0, stream>>>(hpre, rp2, col2, dinv2, b4, outxr, NN, 1);
}

// Round 2
// 628.640 us; speedup vs baseline: 1.2408x; 1.2408x over previous
//
#include <hip/hip_runtime.h>
#include <math.h>

#define NN 50000
#define NE 800000
#define DF 128
#define GEMM_ROWS 64
#define SCAN_M (2 * NN)
#define SCAN_BLKS ((SCAN_M + 1023) / 1024)

// ---------------- combined degree histogram (both graphs, one launch) ----------------
__global__ __launch_bounds__(256) void hist2_kernel(const int* __restrict__ dst1, const int* __restrict__ dst2,
                                                    int* __restrict__ cnt1, int* __restrict__ cnt2, int e) {
    int t = blockIdx.x * 256 + threadIdx.x;
    if (t < e) atomicAdd(&cnt1[dst1[t]], 1);
    else if (t < 2 * e) atomicAdd(&cnt2[dst2[t - e]], 1);
}

// ---------------- scan phase A: per-block exclusive scan + block sums ----------------
__global__ __launch_bounds__(1024) void scanA_kernel(const int* __restrict__ cnt, int* __restrict__ exloc,
                                                     int* __restrict__ bsum) {
    __shared__ int wsum[16];
    const int t = threadIdx.x, lane = t & 63, wid = t >> 6;
    int i = blockIdx.x * 1024 + t;
    int v = (i < SCAN_M) ? cnt[i] : 0;
    int x = v;
    #pragma unroll
    for (int off = 1; off < 64; off <<= 1) { int y = __shfl_up(x, off); if (lane >= off) x += y; }
    if (lane == 63) wsum[wid] = x;
    __syncthreads();
    if (t < 16) {
        int w = wsum[t];
        #pragma unroll
        for (int off = 1; off < 16; off <<= 1) { int y = __shfl_up(w, off); if (t >= off) w += y; }
        wsum[t] = w;
    }
    __syncthreads();
    int excl = (wid ? wsum[wid - 1] : 0) + (x - v);
    if (i < SCAN_M) exloc[i] = excl;
    if (t == 0) bsum[blockIdx.x] = wsum[15];
}

// ---------------- scan phase B: scan the block sums (tiny) ----------------
__global__ __launch_bounds__(128) void scanB_kernel(const int* __restrict__ bsum, int* __restrict__ boff,
                                                    int* __restrict__ rp1, int* __restrict__ rp2) {
    __shared__ int wtot[2];
    const int t = threadIdx.x, lane = t & 63, wid = t >> 6;
    int v = (t < SCAN_BLKS) ? bsum[t] : 0;
    int x = v;
    #pragma unroll
    for (int off = 1; off < 64; off <<= 1) { int y = __shfl_up(x, off); if (lane >= off) x += y; }
    if (lane == 63) wtot[wid] = x;
    __syncthreads();
    int excl = ((wid == 1) ? wtot[0] : 0) + (x - v);
    if (t < SCAN_BLKS) boff[t] = excl;
    if (t == 0) { rp1[NN] = NE; rp2[NN] = NE; }  // graph-1 degree total is exactly NE
}

// ---------------- scan phase C: finalize rp/fill + dinv ----------------
__global__ __launch_bounds__(1024) void scanC_kernel(const int* __restrict__ cnt, const int* __restrict__ exloc,
                                                     const int* __restrict__ boff,
                                                     int* __restrict__ rp1, int* __restrict__ fill1, float* __restrict__ dinv1,
                                                     int* __restrict__ rp2, int* __restrict__ fill2, float* __restrict__ dinv2) {
    int i = blockIdx.x * 1024 + threadIdx.x;
    if (i >= SCAN_M) return;
    int ex = exloc[i] + boff[blockIdx.x];
    float dv = rsqrtf((float)cnt[i] + 1.0f);  // +1 self loop
    if (i < NN) { rp1[i] = ex; fill1[i] = ex; dinv1[i] = dv; }
    else { int j = i - NN; int e2 = ex - NE; rp2[j] = e2; fill2[j] = e2; dinv2[j] = dv; }
}

// ---------------- combined CSR fill (both graphs) with precomputed edge coefs ----------------
__global__ __launch_bounds__(256) void fill2_kernel(const int* __restrict__ src1, const int* __restrict__ dst1,
                                                    const int* __restrict__ src2, const int* __restrict__ dst2,
                                                    int* __restrict__ fill1, int* __restrict__ col1, float* __restrict__ cdv1,
                                                    const float* __restrict__ dinv1,
                                                    int* __restrict__ fillB, int* __restrict__ col2, float* __restrict__ cdv2,
                                                    const float* __restrict__ dinv2, int e) {
    int t = blockIdx.x * 256 + threadIdx.x;
    if (t < e) {
        int d = dst1[t], s = src1[t];
        int p = atomicAdd(&fill1[d], 1);
        col1[p] = s; cdv1[p] = dinv1[s];
    } else if (t < 2 * e) {
        int tt = t - e;
        int d = dst2[tt], s = src2[tt];
        int p = atomicAdd(&fillB[d], 1);
        col2[p] = s; cdv2[p] = dinv2[s];
    }
}

// ---------------- H = X @ W ----------------
// X-tile (64 rows, 32 KB) in LDS read via uniform broadcasts (cheap);
// W (64 KB, L2-resident) streamed as per-lane b128 vmem loads -> no lgkm mixing.
// Thread tile 8 rows x 4 cols; block = 64 rows x 128 cols.
__global__ __launch_bounds__(256) void gemm128_kernel(const float* __restrict__ X, const float* __restrict__ W,
                                                      float* __restrict__ H, int n) {
    __shared__ __align__(16) float Xs[GEMM_ROWS * DF];  // 32 KB -> up to 4 blocks/CU
    const int t = threadIdx.x;
    const int row_base = blockIdx.x * GEMM_ROWS;
    {  // stage X rows (coalesced float4 copy, zero-pad tail rows)
        const float4* X4 = (const float4*)(X + (size_t)row_base * DF);
        float4* Xs4 = (float4*)Xs;
        #pragma unroll
        for (int it = 0; it < (GEMM_ROWS * DF / 4) / 256; it++) {  // 8 iters
            int idx = t + 256 * it;
            int r = idx >> 5;  // 32 float4 per row
            float4 v = make_float4(0.f, 0.f, 0.f, 0.f);
            if (row_base + r < n) v = X4[idx];
            Xs4[idx] = v;
        }
    }
    __syncthreads();
    const int cg = t & 31;   // col group: cols 4*cg .. 4*cg+3
    const int rg = t >> 5;   // row group: local rows rg*8 .. rg*8+7
    const int c0 = cg * 4;
    const int lr0 = rg * 8;
    float4 acc[8];
    #pragma unroll
    for (int r = 0; r < 8; r++) acc[r] = make_float4(0.f, 0.f, 0.f, 0.f);
    #pragma unroll 2
    for (int k0 = 0; k0 < DF; k0 += 4) {
        float4 wv0 = *(const float4*)(W + (size_t)(k0 + 0) * DF + c0);
        float4 wv1 = *(const float4*)(W + (size_t)(k0 + 1) * DF + c0);
        float4 wv2 = *(const float4*)(W + (size_t)(k0 + 2) * DF + c0);
        float4 wv3 = *(const float4*)(W + (size_t)(k0 + 3) * DF + c0);
        #pragma unroll
        for (int r = 0; r < 8; r++) {
            float4 xv = *(const float4*)(Xs + (lr0 + r) * DF + k0);  // quarter-wave-uniform LDS broadcast
            acc[r].x = fmaf(xv.x, wv0.x, acc[r].x); acc[r].y = fmaf(xv.x, wv0.y, acc[r].y);
            acc[r].z = fmaf(xv.x, wv0.z, acc[r].z); acc[r].w = fmaf(xv.x, wv0.w, acc[r].w);
            acc[r].x = fmaf(xv.y, wv1.x, acc[r].x); acc[r].y = fmaf(xv.y, wv1.y, acc[r].y);
            acc[r].z = fmaf(xv.y, wv1.z, acc[r].z); acc[r].w = fmaf(xv.y, wv1.w, acc[r].w);
            acc[r].x = fmaf(xv.z, wv2.x, acc[r].x); acc[r].y = fmaf(xv.z, wv2.y, acc[r].y);
            acc[r].z = fmaf(xv.z, wv2.z, acc[r].z); acc[r].w = fmaf(xv.z, wv2.w, acc[r].w);
            acc[r].x = fmaf(xv.w, wv3.x, acc[r].x); acc[r].y = fmaf(xv.w, wv3.y, acc[r].y);
            acc[r].z = fmaf(xv.w, wv3.z, acc[r].z); acc[r].w = fmaf(xv.w, wv3.w, acc[r].w);
        }
    }
    #pragma unroll
    for (int r = 0; r < 8; r++) {
        int row = row_base + lr0 + r;
        if (row < n) *(float4*)(H + (size_t)row * DF + c0) = acc[r];
    }
}

// ---------------- aggregation: one wave per dst node ----------------
// lane = (half, sub): sub covers 4 cols via float4; halves take alternate edges (2 edges/load-inst).
// out[i] = act( dinv[i]*sum_{e in row i} cdv[e]*H[col[e]] + dinv[i]^2*H[i] + b )
__global__ __launch_bounds__(256) void agg_kernel(const float* __restrict__ H, const int* __restrict__ rp,
                                                  const int* __restrict__ colv, const float* __restrict__ cdv,
                                                  const float* __restrict__ dinv, const float* __restrict__ bias,
                                                  float* __restrict__ out, int n, int act) {
    const int lane = threadIdx.x & 63;
    const int sub = lane & 31;
    const int half = lane >> 5;
    const int i = blockIdx.x * 4 + (threadIdx.x >> 6);
    if (i >= n) return;
    const int start = rp[i];
    const int end = rp[i + 1];
    float ax = 0.f, ay = 0.f, az = 0.f, aw = 0.f;
    const float* __restrict__ Hc = H + 4 * sub;
    for (int base = start; base < end; base += 64) {
        int cnt = end - base;
        if (cnt > 64) cnt = 64;
        int msrc = 0;
        float mdv = 0.f;
        if (lane < cnt) {  // coalesced batch load of edge srcs + coefs
            msrc = colv[base + lane];
            mdv = cdv[base + lane];
        }
        for (int j = 0; j < cnt; j += 8) {  // 8 edges per iter; 4 float4 gathers in flight
            int e0 = j + half;              // halves take even/odd edges; pads have mdv==0
            int s0 = __shfl(msrc, e0),     s1 = __shfl(msrc, e0 + 2);
            int s2 = __shfl(msrc, e0 + 4), s3 = __shfl(msrc, e0 + 6);
            float d0 = __shfl(mdv, e0),     d1 = __shfl(mdv, e0 + 2);
            float d2 = __shfl(mdv, e0 + 4), d3 = __shfl(mdv, e0 + 6);
            float4 h0 = *(const float4*)(Hc + (size_t)s0 * DF);
            float4 h1 = *(const float4*)(Hc + (size_t)s1 * DF);
            float4 h2 = *(const float4*)(Hc + (size_t)s2 * DF);
            float4 h3 = *(const float4*)(Hc + (size_t)s3 * DF);
            ax = fmaf(d0, h0.x, ax); ay = fmaf(d0, h0.y, ay); az = fmaf(d0, h0.z, az); aw = fmaf(d0, h0.w, aw);
            ax = fmaf(d1, h1.x, ax); ay = fmaf(d1, h1.y, ay); az = fmaf(d1, h1.z, az); aw = fmaf(d1, h1.w, aw);
            ax = fmaf(d2, h2.x, ax); ay = fmaf(d2, h2.y, ay); az = fmaf(d2, h2.z, az); aw = fmaf(d2, h2.w, aw);
            ax = fmaf(d3, h3.x, ax); ay = fmaf(d3, h3.y, ay); az = fmaf(d3, h3.z, az); aw = fmaf(d3, h3.w, aw);
        }
    }
    // fold halves: lanes 0-31 += lanes 32-63
    ax += __shfl_down(ax, 32); ay += __shfl_down(ay, 32);
    az += __shfl_down(az, 32); aw += __shfl_down(aw, 32);
    if (half == 0) {
        float di = dinv[i];
        float dii = di * di;
        float4 hv = *(const float4*)(H + (size_t)i * DF + 4 * sub);
        float4 bv = *(const float4*)(bias + 4 * sub);
        float ox = fmaf(di, ax, fmaf(dii, hv.x, bv.x));
        float oy = fmaf(di, ay, fmaf(dii, hv.y, bv.y));
        float oz = fmaf(di, az, fmaf(dii, hv.z, bv.z));
        float ow = fmaf(di, aw, fmaf(dii, hv.w, bv.w));
        if (act == 0) {  // ELU
            ox = ox > 0.f ? ox : expm1f(ox);
            oy = oy > 0.f ? oy : expm1f(oy);
            oz = oz > 0.f ? oz : expm1f(oz);
            ow = ow > 0.f ? ow : expm1f(ow);
        } else {  // ReLU
            ox = fmaxf(ox, 0.f); oy = fmaxf(oy, 0.f);
            oz = fmaxf(oz, 0.f); ow = fmaxf(ow, 0.f);
        }
        float4 ov; ov.x = ox; ov.y = oy; ov.z = oz; ov.w = ow;
        *(float4*)(out + (size_t)i * DF + 4 * sub) = ov;
    }
}

extern "C" void kernel_launch(void* const* d_in, const int* in_sizes, int n_in,
                              void* d_out, int out_size, void* d_ws, size_t ws_size,
                              hipStream_t stream) {
    const float* x  = (const float*)d_in[0];
    const float* W1 = (const float*)d_in[1];
    const float* b1 = (const float*)d_in[2];
    const float* W2 = (const float*)d_in[3];
    const float* b2 = (const float*)d_in[4];
    const float* W3 = (const float*)d_in[5];
    const float* b3 = (const float*)d_in[6];
    const float* W4 = (const float*)d_in[7];
    const float* b4 = (const float*)d_in[8];
    const int* ei1 = (const int*)d_in[9];
    const int* ei2 = (const int*)d_in[10];
    const int *src1 = ei1, *dst1 = ei1 + NE;
    const int *src2 = ei2, *dst2 = ei2 + NE;

    // ---- workspace carve-out (512B aligned), ~66 MB ----
    char* ws = (char*)d_ws;
    size_t off = 0;
    auto carve = [&](size_t bytes) -> void* {
        void* p = (void*)(ws + off);
        off += (bytes + 511) & ~(size_t)511;
        return p;
    };
    int* cnt = (int*)carve((size_t)SCAN_M * 4);   // cnt1 | cnt2 contiguous
    int* cnt1 = cnt;
    int* cnt2 = cnt + NN;
    size_t cnt_bytes = (size_t)SCAN_M * 4;
    float* dinv1 = (float*)carve((size_t)NN * 4);
    float* dinv2 = (float*)carve((size_t)NN * 4);
    int* rp1 = (int*)carve((size_t)(NN + 1) * 4);
    int* rp2 = (int*)carve((size_t)(NN + 1) * 4);
    int* fill1 = (int*)carve((size_t)NN * 4);
    int* fillB = (int*)carve((size_t)NN * 4);
    int* col1 = (int*)carve((size_t)NE * 4);
    int* col2 = (int*)carve((size_t)NE * 4);
    float* cdv1 = (float*)carve((size_t)NE * 4);
    float* cdv2 = (float*)carve((size_t)NE * 4);
    int* bsum = (int*)carve((size_t)SCAN_BLKS * 4);
    int* boff = (int*)carve((size_t)SCAN_BLKS * 4);
    float* hpre = (float*)carve((size_t)NN * DF * 4);
    float* hbuf = (float*)carve((size_t)NN * DF * 4);
    int* exloc = (int*)hpre;  // alias: exloc only live during scan, before first gemm

    float* outz  = (float*)d_out;                     // z  = layer-2 output
    float* outxr = (float*)d_out + (size_t)NN * DF;   // xr = layer-4 output

    const int g2E = (2 * NE + 255) / 256;
    const int gGemm = (NN + GEMM_ROWS - 1) / GEMM_ROWS;
    const int gAgg = (NN + 3) / 4;

    // ---- graph preprocessing ----
    hipMemsetAsync(cnt, 0, cnt_bytes, stream);
    hist2_kernel<<<g2E, 256, 0, stream>>>(dst1, dst2, cnt1, cnt2, NE);
    scanA_kernel<<<SCAN_BLKS, 1024, 0, stream>>>(cnt, exloc, bsum);
    scanB_kernel<<<1, 128, 0, stream>>>(bsum, boff, rp1, rp2);
    scanC_kernel<<<SCAN_BLKS, 1024, 0, stream>>>(cnt, exloc, boff, rp1, fill1, dinv1, rp2, fillB, dinv2);
    fill2_kernel<<<g2E, 256, 0, stream>>>(src1, dst1, src2, dst2,
                                          fill1, col1, cdv1, dinv1,
                                          fillB, col2, cdv2, dinv2, NE);

    // ---- layer 1: ELU(gcn(x, ei1, W1, b1)) -> hbuf ----
    gemm128_kernel<<<gGemm, 256, 0, stream>>>(x, W1, hpre, NN);
    agg_kernel<<<gAgg, 256, 0, stream>>>(hpre, rp1, col1, cdv1, dinv1, b1, hbuf, NN, 0);
    // ---- layer 2: z = ELU(gcn(hbuf, ei2, W2, b2)) -> d_out ----
    gemm128_kernel<<<gGemm, 256, 0, stream>>>(hbuf, W2, hpre, NN);
    agg_kernel<<<gAgg, 256, 0, stream>>>(hpre, rp2, col2, cdv2, dinv2, b2, outz, NN, 0);
    // ---- layer 3: ELU(gcn(z, ei1, W3, b3)) -> hbuf ----
    gemm128_kernel<<<gGemm, 256, 0, stream>>>(outz, W3, hpre, NN);
    agg_kernel<<<gAgg, 256, 0, stream>>>(hpre, rp1, col1, cdv1, dinv1, b3, hbuf, NN, 0);
    // ---- layer 4: xr = ReLU(gcn(hbuf, ei2, W4, b4)) -> d_out[N*DF:] ----
    gemm128_kernel<<<gGemm, 256, 0, stream>>>(hbuf, W4, hpre, NN);
    agg_kernel<<<gAgg, 256, 0, stream>>>(hpre, rp2, col2, cdv2, dinv2, b4, outxr, NN, 1);
}

// Round 3
// 614.975 us; speedup vs baseline: 1.2683x; 1.0222x over previous
//
#include <hip/hip_runtime.h>
#include <math.h>

#define NN 50000
#define NE 800000
#define DF 128
#define GEMM_ROWS 64
#define SCAN_M (2 * NN)
#define SCAN_BLKS ((SCAN_M + 1023) / 1024)
#define NPART 8
#define PART_SZ ((NN + NPART - 1) / NPART)   // 6250
#define PGRID (NPART * 128)                  // partitioned-kernel grid

// ---------------- partitioned degree histogram (both graphs) ----------------
// part = blockIdx % 8 -> XCD round-robin. Each part scans ALL 2E edge slots
// (8x coalesced re-read, cheap) and only counts dsts in its 6250-node range,
// confining atomics to a 25KB window in the local L2.
__global__ __launch_bounds__(256) void hist2p_kernel(const int* __restrict__ dst1, const int* __restrict__ dst2,
                                                     int* __restrict__ cnt1, int* __restrict__ cnt2) {
    const int part = blockIdx.x % NPART;
    const int gid = blockIdx.x / NPART;
    const int nb = gridDim.x / NPART;
    const int lo = part * PART_SZ;
    const int hi = lo + PART_SZ;  // NN divisible by 8 -> no clamp needed
    for (int t = gid * 256 + threadIdx.x; t < 2 * NE; t += nb * 256) {
        int d;
        int* cnt;
        if (t < NE) { d = dst1[t]; cnt = cnt1; }
        else        { d = dst2[t - NE]; cnt = cnt2; }
        if (d >= lo && d < hi) atomicAdd(&cnt[d], 1);
    }
}

// ---------------- scan phase A: per-block exclusive scan + block sums ----------------
__global__ __launch_bounds__(1024) void scanA_kernel(const int* __restrict__ cnt, int* __restrict__ exloc,
                                                     int* __restrict__ bsum) {
    __shared__ int wsum[16];
    const int t = threadIdx.x, lane = t & 63, wid = t >> 6;
    int i = blockIdx.x * 1024 + t;
    int v = (i < SCAN_M) ? cnt[i] : 0;
    int x = v;
    #pragma unroll
    for (int off = 1; off < 64; off <<= 1) { int y = __shfl_up(x, off); if (lane >= off) x += y; }
    if (lane == 63) wsum[wid] = x;
    __syncthreads();
    if (t < 16) {
        int w = wsum[t];
        #pragma unroll
        for (int off = 1; off < 16; off <<= 1) { int y = __shfl_up(w, off); if (t >= off) w += y; }
        wsum[t] = w;
    }
    __syncthreads();
    int excl = (wid ? wsum[wid - 1] : 0) + (x - v);
    if (i < SCAN_M) exloc[i] = excl;
    if (t == 0) bsum[blockIdx.x] = wsum[15];
}

// ---------------- scan phase B: scan the block sums (tiny) ----------------
__global__ __launch_bounds__(128) void scanB_kernel(const int* __restrict__ bsum, int* __restrict__ boff,
                                                    int* __restrict__ rp1, int* __restrict__ rp2) {
    __shared__ int wtot[2];
    const int t = threadIdx.x, lane = t & 63, wid = t >> 6;
    int v = (t < SCAN_BLKS) ? bsum[t] : 0;
    int x = v;
    #pragma unroll
    for (int off = 1; off < 64; off <<= 1) { int y = __shfl_up(x, off); if (lane >= off) x += y; }
    if (lane == 63) wtot[wid] = x;
    __syncthreads();
    int excl = ((wid == 1) ? wtot[0] : 0) + (x - v);
    if (t < SCAN_BLKS) boff[t] = excl;
    if (t == 0) { rp1[NN] = NE; rp2[NN] = NE; }  // graph-1 degree total is exactly NE
}

// ---------------- scan phase C: finalize rp/fill + dinv ----------------
__global__ __launch_bounds__(1024) void scanC_kernel(const int* __restrict__ cnt, const int* __restrict__ exloc,
                                                     const int* __restrict__ boff,
                                                     int* __restrict__ rp1, int* __restrict__ fill1, float* __restrict__ dinv1,
                                                     int* __restrict__ rp2, int* __restrict__ fill2, float* __restrict__ dinv2) {
    int i = blockIdx.x * 1024 + threadIdx.x;
    if (i >= SCAN_M) return;
    int ex = exloc[i] + boff[blockIdx.x];
    float dv = rsqrtf((float)cnt[i] + 1.0f);  // +1 self loop
    if (i < NN) { rp1[i] = ex; fill1[i] = ex; dinv1[i] = dv; }
    else { int j = i - NN; int e2 = ex - NE; rp2[j] = e2; fill2[j] = e2; dinv2[j] = dv; }
}

// ---------------- partitioned CSR fill, packed (src, dinv[src]) int2 entries ----------------
// Same XCD-range partitioning as hist: each part's scattered 8B stores land in
// an ~800KB window -> L2 accumulates ~16 entries/line before write-back.
__global__ __launch_bounds__(256) void fill2p_kernel(const int* __restrict__ src1, const int* __restrict__ dst1,
                                                     const int* __restrict__ src2, const int* __restrict__ dst2,
                                                     int* __restrict__ fill1, int2* __restrict__ pk1,
                                                     const float* __restrict__ dinv1,
                                                     int* __restrict__ fillB, int2* __restrict__ pk2,
                                                     const float* __restrict__ dinv2) {
    const int part = blockIdx.x % NPART;
    const int gid = blockIdx.x / NPART;
    const int nb = gridDim.x / NPART;
    const int lo = part * PART_SZ;
    const int hi = lo + PART_SZ;
    for (int t = gid * 256 + threadIdx.x; t < 2 * NE; t += nb * 256) {
        if (t < NE) {
            int d = dst1[t];
            if (d >= lo && d < hi) {
                int s = src1[t];
                int p = atomicAdd(&fill1[d], 1);
                pk1[p] = make_int2(s, __float_as_int(dinv1[s]));
            }
        } else {
            int tt = t - NE;
            int d = dst2[tt];
            if (d >= lo && d < hi) {
                int s = src2[tt];
                int p = atomicAdd(&fillB[d], 1);
                pk2[p] = make_int2(s, __float_as_int(dinv2[s]));
            }
        }
    }
}

// ---------------- H = X @ W ----------------
// X-tile (64 rows, 32 KB) in LDS read via uniform broadcasts (cheap);
// W (64 KB, L2-resident) streamed as per-lane b128 vmem loads -> no lgkm mixing.
// Thread tile 8 rows x 4 cols; block = 64 rows x 128 cols.
__global__ __launch_bounds__(256) void gemm128_kernel(const float* __restrict__ X, const float* __restrict__ W,
                                                      float* __restrict__ H, int n) {
    __shared__ __align__(16) float Xs[GEMM_ROWS * DF];  // 32 KB
    const int t = threadIdx.x;
    const int row_base = blockIdx.x * GEMM_ROWS;
    {  // stage X rows (coalesced float4 copy, zero-pad tail rows)
        const float4* X4 = (const float4*)(X + (size_t)row_base * DF);
        float4* Xs4 = (float4*)Xs;
        #pragma unroll
        for (int it = 0; it < (GEMM_ROWS * DF / 4) / 256; it++) {  // 8 iters
            int idx = t + 256 * it;
            int r = idx >> 5;  // 32 float4 per row
            float4 v = make_float4(0.f, 0.f, 0.f, 0.f);
            if (row_base + r < n) v = X4[idx];
            Xs4[idx] = v;
        }
    }
    __syncthreads();
    const int cg = t & 31;   // col group: cols 4*cg .. 4*cg+3
    const int rg = t >> 5;   // row group: local rows rg*8 .. rg*8+7
    const int c0 = cg * 4;
    const int lr0 = rg * 8;
    float4 acc[8];
    #pragma unroll
    for (int r = 0; r < 8; r++) acc[r] = make_float4(0.f, 0.f, 0.f, 0.f);
    #pragma unroll 4
    for (int k0 = 0; k0 < DF; k0 += 4) {
        float4 wv0 = *(const float4*)(W + (size_t)(k0 + 0) * DF + c0);
        float4 wv1 = *(const float4*)(W + (size_t)(k0 + 1) * DF + c0);
        float4 wv2 = *(const float4*)(W + (size_t)(k0 + 2) * DF + c0);
        float4 wv3 = *(const float4*)(W + (size_t)(k0 + 3) * DF + c0);
        #pragma unroll
        for (int r = 0; r < 8; r++) {
            float4 xv = *(const float4*)(Xs + (lr0 + r) * DF + k0);  // quarter-wave-uniform LDS broadcast
            acc[r].x = fmaf(xv.x, wv0.x, acc[r].x); acc[r].y = fmaf(xv.x, wv0.y, acc[r].y);
            acc[r].z = fmaf(xv.x, wv0.z, acc[r].z); acc[r].w = fmaf(xv.x, wv0.w, acc[r].w);
            acc[r].x = fmaf(xv.y, wv1.x, acc[r].x); acc[r].y = fmaf(xv.y, wv1.y, acc[r].y);
            acc[r].z = fmaf(xv.y, wv1.z, acc[r].z); acc[r].w = fmaf(xv.y, wv1.w, acc[r].w);
            acc[r].x = fmaf(xv.z, wv2.x, acc[r].x); acc[r].y = fmaf(xv.z, wv2.y, acc[r].y);
            acc[r].z = fmaf(xv.z, wv2.z, acc[r].z); acc[r].w = fmaf(xv.z, wv2.w, acc[r].w);
            acc[r].x = fmaf(xv.w, wv3.x, acc[r].x); acc[r].y = fmaf(xv.w, wv3.y, acc[r].y);
            acc[r].z = fmaf(xv.w, wv3.z, acc[r].z); acc[r].w = fmaf(xv.w, wv3.w, acc[r].w);
        }
    }
    #pragma unroll
    for (int r = 0; r < 8; r++) {
        int row = row_base + lr0 + r;
        if (row < n) *(float4*)(H + (size_t)row * DF + c0) = acc[r];
    }
}

// ---------------- aggregation: one wave per dst node ----------------
// lane = (half, sub): sub covers 4 cols via float4; halves take alternate edges.
// out[i] = act( dinv[i]*sum_{e in row i} coef[e]*H[src[e]] + dinv[i]^2*H[i] + b )
__global__ __launch_bounds__(256) void agg_kernel(const float* __restrict__ H, const int* __restrict__ rp,
                                                  const int2* __restrict__ pk,
                                                  const float* __restrict__ dinv, const float* __restrict__ bias,
                                                  float* __restrict__ out, int n, int act) {
    const int lane = threadIdx.x & 63;
    const int sub = lane & 31;
    const int half = lane >> 5;
    const int i = blockIdx.x * 4 + (threadIdx.x >> 6);
    if (i >= n) return;
    const int start = rp[i];
    const int end = rp[i + 1];
    float ax = 0.f, ay = 0.f, az = 0.f, aw = 0.f;
    const float* __restrict__ Hc = H + 4 * sub;
    for (int base = start; base < end; base += 64) {
        int cnt = end - base;
        if (cnt > 64) cnt = 64;
        int msrc = 0;
        float mdv = 0.f;
        if (lane < cnt) {  // coalesced 8B batch load of packed (src, coef)
            int2 pv = pk[base + lane];
            msrc = pv.x;
            mdv = __int_as_float(pv.y);
        }
        for (int j = 0; j < cnt; j += 8) {  // 8 edges per iter; 4 float4 gathers in flight
            int e0 = j + half;              // halves take even/odd edges; pads have mdv==0
            int s0 = __shfl(msrc, e0),     s1 = __shfl(msrc, e0 + 2);
            int s2 = __shfl(msrc, e0 + 4), s3 = __shfl(msrc, e0 + 6);
            float d0 = __shfl(mdv, e0),     d1 = __shfl(mdv, e0 + 2);
            float d2 = __shfl(mdv, e0 + 4), d3 = __shfl(mdv, e0 + 6);
            float4 h0 = *(const float4*)(Hc + (size_t)s0 * DF);
            float4 h1 = *(const float4*)(Hc + (size_t)s1 * DF);
            float4 h2 = *(const float4*)(Hc + (size_t)s2 * DF);
            float4 h3 = *(const float4*)(Hc + (size_t)s3 * DF);
            ax = fmaf(d0, h0.x, ax); ay = fmaf(d0, h0.y, ay); az = fmaf(d0, h0.z, az); aw = fmaf(d0, h0.w, aw);
            ax = fmaf(d1, h1.x, ax); ay = fmaf(d1, h1.y, ay); az = fmaf(d1, h1.z, az); aw = fmaf(d1, h1.w, aw);
            ax = fmaf(d2, h2.x, ax); ay = fmaf(d2, h2.y, ay); az = fmaf(d2, h2.z, az); aw = fmaf(d2, h2.w, aw);
            ax = fmaf(d3, h3.x, ax); ay = fmaf(d3, h3.y, ay); az = fmaf(d3, h3.z, az); aw = fmaf(d3, h3.w, aw);
        }
    }
    // fold halves: lanes 0-31 += lanes 32-63
    ax += __shfl_down(ax, 32); ay += __shfl_down(ay, 32);
    az += __shfl_down(az, 32); aw += __shfl_down(aw, 32);
    if (half == 0) {
        float di = dinv[i];
        float dii = di * di;
        float4 hv = *(const float4*)(H + (size_t)i * DF + 4 * sub);
        float4 bv = *(const float4*)(bias + 4 * sub);
        float ox = fmaf(di, ax, fmaf(dii, hv.x, bv.x));
        float oy = fmaf(di, ay, fmaf(dii, hv.y, bv.y));
        float oz = fmaf(di, az, fmaf(dii, hv.z, bv.z));
        float ow = fmaf(di, aw, fmaf(dii, hv.w, bv.w));
        if (act == 0) {  // ELU
            ox = ox > 0.f ? ox : expm1f(ox);
            oy = oy > 0.f ? oy : expm1f(oy);
            oz = oz > 0.f ? oz : expm1f(oz);
            ow = ow > 0.f ? ow : expm1f(ow);
        } else {  // ReLU
            ox = fmaxf(ox, 0.f); oy = fmaxf(oy, 0.f);
            oz = fmaxf(oz, 0.f); ow = fmaxf(ow, 0.f);
        }
        float4 ov; ov.x = ox; ov.y = oy; ov.z = oz; ov.w = ow;
        *(float4*)(out + (size_t)i * DF + 4 * sub) = ov;
    }
}

extern "C" void kernel_launch(void* const* d_in, const int* in_sizes, int n_in,
                              void* d_out, int out_size, void* d_ws, size_t ws_size,
                              hipStream_t stream) {
    const float* x  = (const float*)d_in[0];
    const float* W1 = (const float*)d_in[1];
    const float* b1 = (const float*)d_in[2];
    const float* W2 = (const float*)d_in[3];
    const float* b2 = (const float*)d_in[4];
    const float* W3 = (const float*)d_in[5];
    const float* b3 = (const float*)d_in[6];
    const float* W4 = (const float*)d_in[7];
    const float* b4 = (const float*)d_in[8];
    const int* ei1 = (const int*)d_in[9];
    const int* ei2 = (const int*)d_in[10];
    const int *src1 = ei1, *dst1 = ei1 + NE;
    const int *src2 = ei2, *dst2 = ei2 + NE;

    // ---- workspace carve-out (512B aligned), ~66 MB ----
    char* ws = (char*)d_ws;
    size_t off = 0;
    auto carve = [&](size_t bytes) -> void* {
        void* p = (void*)(ws + off);
        off += (bytes + 511) & ~(size_t)511;
        return p;
    };
    int* cnt = (int*)carve((size_t)SCAN_M * 4);   // cnt1 | cnt2 contiguous
    int* cnt1 = cnt;
    int* cnt2 = cnt + NN;
    size_t cnt_bytes = (size_t)SCAN_M * 4;
    float* dinv1 = (float*)carve((size_t)NN * 4);
    float* dinv2 = (float*)carve((size_t)NN * 4);
    int* rp1 = (int*)carve((size_t)(NN + 1) * 4);
    int* rp2 = (int*)carve((size_t)(NN + 1) * 4);
    int* fill1 = (int*)carve((size_t)NN * 4);
    int* fillB = (int*)carve((size_t)NN * 4);
    int2* pk1 = (int2*)carve((size_t)NE * 8);
    int2* pk2 = (int2*)carve((size_t)NE * 8);
    int* bsum = (int*)carve((size_t)SCAN_BLKS * 4);
    int* boff = (int*)carve((size_t)SCAN_BLKS * 4);
    float* hpre = (float*)carve((size_t)NN * DF * 4);
    float* hbuf = (float*)carve((size_t)NN * DF * 4);
    int* exloc = (int*)hpre;  // alias: exloc only live during scan, before first gemm

    float* outz  = (float*)d_out;                     // z  = layer-2 output
    float* outxr = (float*)d_out + (size_t)NN * DF;   // xr = layer-4 output

    const int gGemm = (NN + GEMM_ROWS - 1) / GEMM_ROWS;
    const int gAgg = (NN + 3) / 4;

    // ---- graph preprocessing ----
    hipMemsetAsync(cnt, 0, cnt_bytes, stream);
    hist2p_kernel<<<PGRID, 256, 0, stream>>>(dst1, dst2, cnt1, cnt2);
    scanA_kernel<<<SCAN_BLKS, 1024, 0, stream>>>(cnt, exloc, bsum);
    scanB_kernel<<<1, 128, 0, stream>>>(bsum, boff, rp1, rp2);
    scanC_kernel<<<SCAN_BLKS, 1024, 0, stream>>>(cnt, exloc, boff, rp1, fill1, dinv1, rp2, fillB, dinv2);
    fill2p_kernel<<<PGRID, 256, 0, stream>>>(src1, dst1, src2, dst2,
                                             fill1, pk1, dinv1,
                                             fillB, pk2, dinv2);

    // ---- layer 1: ELU(gcn(x, ei1, W1, b1)) -> hbuf ----
    gemm128_kernel<<<gGemm, 256, 0, stream>>>(x, W1, hpre, NN);
    agg_kernel<<<gAgg, 256, 0, stream>>>(hpre, rp1, pk1, dinv1, b1, hbuf, NN, 0);
    // ---- layer 2: z = ELU(gcn(hbuf, ei2, W2, b2)) -> d_out ----
    gemm128_kernel<<<gGemm, 256, 0, stream>>>(hbuf, W2, hpre, NN);
    agg_kernel<<<gAgg, 256, 0, stream>>>(hpre, rp2, pk2, dinv2, b2, outz, NN, 0);
    // ---- layer 3: ELU(gcn(z, ei1, W3, b3)) -> hbuf ----
    gemm128_kernel<<<gGemm, 256, 0, stream>>>(outz, W3, hpre, NN);
    agg_kernel<<<gAgg, 256, 0, stream>>>(hpre, rp1, pk1, dinv1, b3, hbuf, NN, 0);
    // ---- layer 4: xr = ReLU(gcn(hbuf, ei2, W4, b4)) -> d_out[N*DF:] ----
    gemm128_kernel<<<gGemm, 256, 0, stream>>>(hbuf, W4, hpre, NN);
    agg_kernel<<<gAgg, 256, 0, stream>>>(hpre, rp2, pk2, dinv2, b4, outxr, NN, 1);
}